// Round 8
// baseline (12180.045 us; speedup 1.0000x reference)
//
#include <hip/hip_runtime.h>

#define Hd 1024
#define Sd 4096
#define G4 4096   // 4*H

typedef __attribute__((ext_vector_type(8))) short    bf16x8;
typedef __attribute__((ext_vector_type(8))) unsigned short u16x8;
typedef __attribute__((ext_vector_type(2))) unsigned u32x2;
typedef __attribute__((ext_vector_type(4))) unsigned u32x4;
typedef __attribute__((ext_vector_type(4))) float    f32x4;

// ---- ws layout (bytes) ----
#define WS_WHH_F 0u                 // 4096*1024*2 = 8388608
#define WS_WIH_F 8388608u           // 8388608
#define WS_EMB_F 16777216u          // 8388608 (dead after gemm_k; hrec reuses its head)
#define WS_HREC  16777216u          // 2 buffers x 256 chunks x 16B = 8192
#define WS_XG    25165824u          // 4096*4096*2 = 33554432
#define WS_BIAS  58720256u          // 4096*4 = 16384

#define AS1 __attribute__((address_space(1)))
#define AS3 __attribute__((address_space(3)))

__device__ __forceinline__ float b2f(unsigned short u) {
    return __uint_as_float(((unsigned)u) << 16);
}
__device__ __forceinline__ unsigned short f2b(float f) {
    unsigned u = __float_as_uint(f);
    unsigned r = u + 0x7fffu + ((u >> 16) & 1u);   // RNE
    return (unsigned short)(r >> 16);
}
__device__ __forceinline__ float sigmoid_fast(float x) {
    return 1.f / (1.f + __expf(-x));   // inf-safe at both ends
}
__device__ __forceinline__ float tanh_fast(float x) {
    float e = __expf(2.f * fabsf(x));  // inf-safe: 2/(inf+1)=0 -> +-1
    return copysignf(1.f - 2.f / (e + 1.f), x);
}

// Pack a [R x 1024] f32 matrix (optionally row-gathered by idx) into MFMA
// A-fragment order: chunk(rb,kb) = 64 lanes x 8 bf16,
// elem(l,j) = src[rb*16 + (l&15)][kb*32 + (l>>4)*8 + j]
__global__ void pack_frag(const float* __restrict__ src, const int* __restrict__ idx,
                          unsigned short* __restrict__ dst) {
    const int rb = blockIdx.x;       // 0..255
    const int kb = blockIdx.y;       // 0..31
    const int l  = threadIdx.x;      // 0..63
    int row = rb * 16 + (l & 15);
    if (idx) row = idx[row];
    const float* s = src + (size_t)row * Hd + kb * 32 + ((l >> 4) & 3) * 8;
    float4 f0 = *(const float4*)s;
    float4 f1 = *(const float4*)(s + 4);
    u16x8 v;
    v[0]=f2b(f0.x); v[1]=f2b(f0.y); v[2]=f2b(f0.z); v[3]=f2b(f0.w);
    v[4]=f2b(f1.x); v[5]=f2b(f1.y); v[6]=f2b(f1.z); v[7]=f2b(f1.w);
    *(u16x8*)(dst + ((size_t)(rb * 32 + kb) * 64 + l) * 8) = v;
}

__global__ void init_k(const float* __restrict__ bih, const float* __restrict__ bhh,
                       float* __restrict__ bias) {
    const int i = blockIdx.x * 256 + threadIdx.x;   // 0..4095
    bias[i] = bih[i] + bhh[i];
}

// zero BOTH hrec buffers (tags 0; garbage in buf1 could alias a future tag).
__global__ void zero_hrec_k(unsigned* __restrict__ hrec) {
    hrec[blockIdx.x * 256 + threadIdx.x] = 0u;      // 2048 dwords
}

// xg[s][n] = sum_k embs[s][k]*W_ih[n][k] + bias[n], bf16 out.
__global__ __launch_bounds__(256, 2)
void gemm_k(const unsigned short* __restrict__ Af, const unsigned short* __restrict__ Bf,
            const float* __restrict__ bias, unsigned short* __restrict__ xg) {
    const int w = threadIdx.x >> 6, l = threadIdx.x & 63;
    const int wid = blockIdx.x * 4 + w;      // 0..4095
    const int mg = wid >> 6;                 // 0..63
    const int ng = wid & 63;                 // 0..63

    f32x4 acc[4][4] = {};
    for (int kb = 0; kb < 32; ++kb) {
        bf16x8 a[4], b[4];
#pragma unroll
        for (int mi = 0; mi < 4; ++mi)
            a[mi] = *(const bf16x8*)(Af + (((size_t)(mg * 4 + mi) * 32 + kb) * 64 + l) * 8);
#pragma unroll
        for (int ni = 0; ni < 4; ++ni)
            b[ni] = *(const bf16x8*)(Bf + (((size_t)(ng * 4 + ni) * 32 + kb) * 64 + l) * 8);
#pragma unroll
        for (int mi = 0; mi < 4; ++mi)
#pragma unroll
            for (int ni = 0; ni < 4; ++ni)
                acc[mi][ni] = __builtin_amdgcn_mfma_f32_16x16x32_bf16(a[mi], b[ni], acc[mi][ni], 0, 0, 0);
    }
    const int r4 = (l >> 4) * 4, c = l & 15;
#pragma unroll
    for (int ni = 0; ni < 4; ++ni) {
        const int col = ng * 64 + ni * 16 + c;
        const float bv = bias[col];
#pragma unroll
        for (int mi = 0; mi < 4; ++mi) {
            const int rowb = mg * 64 + mi * 16 + r4;
#pragma unroll
            for (int i = 0; i < 4; ++i)
                xg[(size_t)(rowb + i) * G4 + col] = f2b(acc[mi][ni][i] + bv);
        }
    }
}

// Persistent LSTM scan. 32 WGs x 256 thr. WG r owns h[r*32, r*32+32).
// Wave w = gate w (2 row-blocks, 64 MFMAs, W_hh in 256 VGPRs).
// Transport (r4-proven): 256 dual-tagged 16B chunks at LLC scope (sc0 sc1).
// NEW: detection via a 4-slot per-wave LDS ring of global_load_lds polls
// (no VGPR dest -> stale in-flight loads are harmless), exact vmcnt(3) FIFO
// waits, asm ds_read tag checks. Bounded drained fallback = r4 correctness.
__global__ __launch_bounds__(256, 1)
void scan_k(const unsigned short* __restrict__ Wf, const unsigned short* __restrict__ xg,
            unsigned* __restrict__ hrec, float* __restrict__ out) {
    __shared__ unsigned h_sw[512];        // full h as 512 dwords (1024 bf16)
    __shared__ float g_lds[128];          // [gate 0..3][lh 0..31]
    __shared__ unsigned poll_lds[4096];   // 4 slots x 256 chunks x 4 dw = 16KB

    const int role = blockIdx.x;          // 0..31
    const int tid  = threadIdx.x;         // == this thread's chunk index
    const int w = tid >> 6, l = tid & 63;
    const int rb0 = (w << 6) + role * 2;  // first of 2 row-blocks (gate w)

    bf16x8 wfrag[64];                     // 256 VGPRs of W_hh
#pragma unroll
    for (int kb = 0; kb < 32; ++kb) {
        wfrag[kb * 2]     = *(const bf16x8*)(Wf + (((size_t)rb0       * 32 + kb) * 64 + l) * 8);
        wfrag[kb * 2 + 1] = *(const bf16x8*)(Wf + (((size_t)(rb0 + 1) * 32 + kb) * 64 + l) * 8);
    }

    const unsigned poll_base = (unsigned)(size_t)(AS3 const void*)&poll_lds[0];
    float c_reg = 0.f;                    // wave0 lanes<32: cell state
    const int hoff = ((l >> 4) & 3) * 8;
    const int r0 = (l >> 4) << 2;
    const unsigned short* h_ss = (const unsigned short*)h_sw;

    for (int t = 0; t < Sd; ++t) {
        const unsigned tt = (unsigned)t;
        const unsigned* gp = hrec + (t & 1) * 1024 + tid * 4;   // my chunk (per-lane)

        // xg for this step: asm loads, retired by the ring's first vmcnt(3)
        u32x2 xva, xvb;
        {
            const unsigned short* xp = xg + (size_t)t * G4 + (w << 10) + (role << 5) + r0;
            asm volatile("global_load_dwordx2 %0, %1, off" : "=v"(xva) : "v"(xp) : "memory");
            asm volatile("global_load_dwordx2 %0, %1, off" : "=v"(xvb) : "v"(xp + 16) : "memory");
        }

        // ---- issue 4 ring polls (slots 0..3), then check-oldest / reissue ----
#pragma unroll
        for (int s4 = 0; s4 < 4; ++s4)
            __builtin_amdgcn_global_load_lds((const AS1 void*)gp,
                (AS3 void*)&poll_lds[s4 * 1024 + w * 256], 16, 0, 17 /*sc0|sc1*/);
        int s = 0, ring_ok = 0;
        unsigned sbase = 0;
        for (int checks = 0; checks < 16; ++checks) {
            asm volatile("s_waitcnt vmcnt(3)" ::: "memory");   // oldest slot retired (FIFO)
            __builtin_amdgcn_sched_barrier(0);
            sbase = poll_base + (unsigned)(s * 4096 + w * 1024 + l * 16);
            u32x2 tg;
            asm volatile("ds_read2_b32 %0, %1 offset0:1 offset1:3" : "=v"(tg) : "v"(sbase));
            asm volatile("s_waitcnt lgkmcnt(0)" ::: "memory");
            __builtin_amdgcn_sched_barrier(0);
            if (!__any((tg[0] != tt) | (tg[1] != tt))) { ring_ok = 1; break; }
            __builtin_amdgcn_global_load_lds((const AS1 void*)gp,
                (AS3 void*)&poll_lds[s * 1024 + w * 256], 16, 0, 17);
            s = (s + 1) & 3;
        }
        unsigned g0, g1;
        if (ring_ok) {
            u32x2 pl;
            asm volatile("ds_read2_b32 %0, %1 offset0:0 offset1:2" : "=v"(pl) : "v"(sbase));
            asm volatile("s_waitcnt lgkmcnt(0)" ::: "memory");
            __builtin_amdgcn_sched_barrier(0);
            g0 = pl[0]; g1 = pl[1];
        } else {
            // r4-proven drained fallback (always correct; bounded)
            u32x4 pA = {0, 0, 0, 0};
            int guard = 0;
            while (true) {
                asm volatile("global_load_dwordx4 %0, %1, off sc0 sc1\n\ts_waitcnt vmcnt(0)"
                             : "=v"(pA) : "v"(gp) : "memory");
                __builtin_amdgcn_sched_barrier(0);
                if (!__any((pA[1] != tt) | (pA[3] != tt))) break;
                if (++guard > 64) break;   // bounded: wrong, never hang
                __builtin_amdgcn_s_sleep(1);
            }
            g0 = pA[0]; g1 = pA[2];
        }
        h_sw[tid * 2]     = g0;
        h_sw[tid * 2 + 1] = g1;
        asm volatile("s_waitcnt lgkmcnt(0)" ::: "memory");
        __builtin_amdgcn_s_barrier();                          // B1
        __builtin_amdgcn_sched_barrier(0);

        // ---- 64 MFMAs: 4 interleaved 16-deep chains ----
        f32x4 a00 = {0,0,0,0}, a01 = {0,0,0,0}, a10 = {0,0,0,0}, a11 = {0,0,0,0};
#pragma unroll
        for (int kb = 0; kb < 32; kb += 2) {
            bf16x8 hf0 = *(const bf16x8*)(h_ss + kb * 32 + hoff);
            bf16x8 hf1 = *(const bf16x8*)(h_ss + (kb + 1) * 32 + hoff);
            a00 = __builtin_amdgcn_mfma_f32_16x16x32_bf16(wfrag[kb * 2],           hf0, a00, 0, 0, 0);
            a10 = __builtin_amdgcn_mfma_f32_16x16x32_bf16(wfrag[kb * 2 + 1],       hf0, a10, 0, 0, 0);
            a01 = __builtin_amdgcn_mfma_f32_16x16x32_bf16(wfrag[(kb + 1) * 2],     hf1, a01, 0, 0, 0);
            a11 = __builtin_amdgcn_mfma_f32_16x16x32_bf16(wfrag[(kb + 1) * 2 + 1], hf1, a11, 0, 0, 0);
        }
        f32x4 acc0 = a00 + a01, acc1 = a10 + a11;

        if ((l & 15) == 0) {   // lanes 0,16,32,48: rows r0..r0+3 of each row-block
            g_lds[(w << 5) + r0 + 0]      = acc0[0] + b2f((unsigned short)(xva[0] & 0xffffu));
            g_lds[(w << 5) + r0 + 1]      = acc0[1] + b2f((unsigned short)(xva[0] >> 16));
            g_lds[(w << 5) + r0 + 2]      = acc0[2] + b2f((unsigned short)(xva[1] & 0xffffu));
            g_lds[(w << 5) + r0 + 3]      = acc0[3] + b2f((unsigned short)(xva[1] >> 16));
            g_lds[(w << 5) + 16 + r0 + 0] = acc1[0] + b2f((unsigned short)(xvb[0] & 0xffffu));
            g_lds[(w << 5) + 16 + r0 + 1] = acc1[1] + b2f((unsigned short)(xvb[0] >> 16));
            g_lds[(w << 5) + 16 + r0 + 2] = acc1[2] + b2f((unsigned short)(xvb[1] & 0xffffu));
            g_lds[(w << 5) + 16 + r0 + 3] = acc1[3] + b2f((unsigned short)(xvb[1] >> 16));
        }
        asm volatile("s_waitcnt lgkmcnt(0)" ::: "memory");
        __builtin_amdgcn_s_barrier();                          // B2
        __builtin_amdgcn_sched_barrier(0);

        // ---- wave0: LSTM cell for this WG's 32 h-lanes; publish chunks ----
        if (w == 0) {
            float h = 0.f; unsigned short hb = 0;
            if (l < 32) {
                float iv = sigmoid_fast(g_lds[l]);
                float fv = sigmoid_fast(g_lds[32 + l]);
                float gv = tanh_fast(g_lds[64 + l]);
                float ov = sigmoid_fast(g_lds[96 + l]);
                float c = fv * c_reg + iv * gv;
                c_reg = c;
                h = ov * tanh_fast(c);
                hb = f2b(h);
                out[(size_t)Hd + (size_t)t * Hd + (role << 5) + l] = h;   // outs[t]
                if (t == Sd - 1) out[(role << 5) + l] = h;                // final h
            }
            unsigned p  = (unsigned)hb | ((unsigned)__shfl_xor((int)(unsigned)hb, 1, 64) << 16);
            unsigned p2 = (unsigned)__shfl((int)p, (l & ~3) + 2, 64);
            if (l < 32 && (l & 3) == 0) {
                const unsigned tag = tt + 1u;
                u32x4 val = {p, tag, p2, tag};
                unsigned* dst = hrec + ((t + 1) & 1) * 1024 + ((role << 3) + (l >> 2)) * 4;
                asm volatile("global_store_dwordx4 %0, %1, off sc0 sc1"
                             :: "v"(dst), "v"(val) : "memory");
            }
        }
        // fire-and-forget: next step's vmcnt(3) FIFO-drains the store acks.
    }
}

extern "C" void kernel_launch(void* const* d_in, const int* in_sizes, int n_in,
                              void* d_out, int out_size, void* d_ws, size_t ws_size,
                              hipStream_t stream) {
    (void)in_sizes; (void)n_in; (void)out_size; (void)ws_size;
    const int*   x   = (const int*)  d_in[0];
    const float* emb = (const float*)d_in[1];
    const float* Wih = (const float*)d_in[2];
    const float* Whh = (const float*)d_in[3];
    const float* bih = (const float*)d_in[4];
    const float* bhh = (const float*)d_in[5];
    float* out = (float*)d_out;

    char* ws = (char*)d_ws;
    unsigned short* whh_f = (unsigned short*)(ws + WS_WHH_F);
    unsigned short* wih_f = (unsigned short*)(ws + WS_WIH_F);
    unsigned short* emb_f = (unsigned short*)(ws + WS_EMB_F);
    unsigned short* xgp   = (unsigned short*)(ws + WS_XG);
    float*          bias  = (float*)        (ws + WS_BIAS);
    unsigned*       hrec  = (unsigned*)      (ws + WS_HREC);

    init_k     <<<16, 256, 0, stream>>>(bih, bhh, bias);
    pack_frag  <<<dim3(256, 32), 64, 0, stream>>>(Whh, nullptr, whh_f);
    pack_frag  <<<dim3(256, 32), 64, 0, stream>>>(Wih, nullptr, wih_f);
    pack_frag  <<<dim3(256, 32), 64, 0, stream>>>(emb, x,       emb_f);
    gemm_k     <<<1024, 256, 0, stream>>>(emb_f, wih_f, bias, xgp);
    zero_hrec_k<<<8, 256, 0, stream>>>(hrec);          // after gemm: hrec aliases emb_f
    scan_k     <<<32, 256, 0, stream>>>(whh_f, xgp, hrec, out);
}